// Round 8
// baseline (95.263 us; speedup 1.0000x reference)
//
#include <hip/hip_runtime.h>
#include <hip/hip_fp16.h>
#include <math.h>

#define HWPX 262144   // 512*512
#define NIMG 8
#define ACC_STRIDE 96
#define NB 1024       // histogram bins (e-space for P, z-space for Q)
#define ZMAX 8.0f
#define NSPLIT 32
#define NGRP 2
#define STAT_GRID 2048   // 256 blocks/image, 1024 px/block, 4 px/thread
// accd layout per image (doubles):
// [80] bg_seed, [81] fit_seed(acc), [82] inst_loss(acc), [83] var_loss, [84] obj

typedef unsigned long long u64;

__device__ __forceinline__ float tanh_fast(float x) {
  float t = __expf(2.0f * x);
  return 1.0f - __fdividef(2.0f, t + 1.0f);
}
__device__ __forceinline__ float sigmoid_fast(float x) {
  return __fdividef(1.0f, 1.0f + __expf(-x));
}

// ---------- pass 1: register-accumulated stats partials (+ packed records). ----------
// NO LDS atomics, NO divergent stat path: per-thread mask-FMA into 80 registers,
// then shuffle-tree + tiny LDS cross-wave merge.
template<bool PACK>
__global__ __launch_bounds__(256) void k_stats(const float* __restrict__ pred,
    const int* __restrict__ inst, const int* __restrict__ lab,
    u64* __restrict__ rec, float* __restrict__ part)
{
  __shared__ float sred[4][96];
  int t = threadIdx.x;
  int bid = blockIdx.x;
  int b = bid >> 8;                       // 256 blocks per image
  int px0 = ((bid & 255) << 10) + t*4;    // 4 consecutive px per thread (same row)
  const float* pb = pred + (size_t)b*4*HWPX;
  size_t ib = (size_t)b*HWPX;
  int w0 = px0 & 511;
  float ym = (float)(px0 >> 9) * (1.0f/1023.0f);

  float4 X  = *(const float4*)(pb + px0);
  float4 Y  = *(const float4*)(pb + HWPX + px0);
  float4 Gv = *(const float4*)(pb + 2*HWPX + px0);
  float4 Q  = *(const float4*)(pb + 3*HWPX + px0);
  int4   L  = *(const int4*)(lab + ib + px0);
  int4   I  = *(const int4*)(inst + ib + px0);

  float cnt[16], sx[16], sy[16], ss[16], s2[16];
  #pragma unroll
  for (int j = 0; j < 16; ++j) { cnt[j]=0.f; sx[j]=0.f; sy[j]=0.f; ss[j]=0.f; s2[j]=0.f; }
  float bg = 0.0f;
  u64 rv0 = 0, rv1 = 0, rv2 = 0, rv3 = 0;

#define PXR(RV, C, XX, YY, GG, QQ, LL, II) { \
    float xm = (float)(w0 + C) * (1.0f/1023.0f); \
    float sd = sigmoid_fast(QQ); \
    int mid = ((LL) == 1 && (unsigned)((II)-1) < 16u) ? (II) : 0; \
    if (PACK) { \
      float ex = tanh_fast(XX) + xm; \
      float ey = tanh_fast(YY) + ym; \
      RV = (u64)__half_as_ushort(__float2half(ex)) \
         | ((u64)__half_as_ushort(__float2half(ey)) << 16) \
         | ((u64)__half_as_ushort(__float2half(sd)) << 32) \
         | ((u64)mid << 48); \
    } \
    bg += ((LL) == 0) ? sd*sd : 0.0f; \
    float gg = (GG), gg2 = (GG)*(GG); \
    _Pragma("unroll") \
    for (int j = 0; j < 16; ++j) { \
      float m = (mid == j+1) ? 1.0f : 0.0f; \
      cnt[j] += m; \
      sx[j] = fmaf(m, xm, sx[j]); \
      sy[j] = fmaf(m, ym, sy[j]); \
      ss[j] = fmaf(m, gg, ss[j]); \
      s2[j] = fmaf(m, gg2, s2[j]); \
    } }

  PXR(rv0, 0, X.x, Y.x, Gv.x, Q.x, L.x, I.x)
  PXR(rv1, 1, X.y, Y.y, Gv.y, Q.y, L.y, I.y)
  PXR(rv2, 2, X.z, Y.z, Gv.z, Q.z, L.z, I.z)
  PXR(rv3, 3, X.w, Y.w, Gv.w, Q.w, L.w, I.w)
#undef PXR

  if (PACK) {
    ulonglong2* rp = (ulonglong2*)(rec + ib + px0);
    rp[0] = make_ulonglong2(rv0, rv1);
    rp[1] = make_ulonglong2(rv2, rv3);
  }

  int wv = t >> 6, ln = t & 63;
#define WRED(V, IDX) { \
    float v = (V); \
    _Pragma("unroll") \
    for (int o = 32; o > 0; o >>= 1) v += __shfl_down(v, o); \
    if (ln == 0) sred[wv][IDX] = v; }
  #pragma unroll
  for (int j = 0; j < 16; ++j) {
    WRED(cnt[j], j)
    WRED(sx[j], 16+j)
    WRED(sy[j], 32+j)
    WRED(ss[j], 48+j)
    WRED(s2[j], 64+j)
  }
  WRED(bg, 80)
#undef WRED
  __syncthreads();
  if (t < 96) {
    float v = 0.0f;
    if (t < 81) {
      #pragma unroll
      for (int w = 0; w < 4; ++w) v += sred[w][t];
    }
    part[(size_t)bid*96 + t] = v;
  }
}

// ---------- pass 1b: reduce 256 partials/image, finalize pairinfo + accd ----------
__global__ __launch_bounds__(1024) void k_fin(const float* __restrict__ part,
    double* __restrict__ accd, float* __restrict__ pairinfo)
{
  __shared__ float red2[10*96];
  int t = threadIdx.x, b = blockIdx.x;
  if (t < 960) {
    int e = t % 96, c = t / 96;
    int lo = c*26, hi = lo + 26; if (hi > 256) hi = 256;
    const float* pp = part + (size_t)b*256*96 + e;
    float v = 0.0f;
    for (int blk = lo; blk < hi; ++blk) v += pp[(size_t)blk*96];
    red2[c*96 + e] = v;
  }
  __syncthreads();
  if (t < 96) {
    float v = 0.0f;
    #pragma unroll
    for (int cc = 0; cc < 10; ++cc) v += red2[cc*96 + t];
    red2[t] = v;
  }
  __syncthreads();
  if (t < 16) {
    float cnt = red2[t];
    float safe = cnt > 0.0f ? cnt : 1.0f;
    float sm = red2[48+t] / safe;
    float4 pi = make_float4(red2[16+t]/safe, red2[32+t]/safe, __expf(10.0f*sm), cnt);
    ((float4*)pairinfo)[b*16 + t] = pi;
  }
  if (t == 0) {
    double vs = 0.0; float np = 0.0f;
    for (int k2 = 0; k2 < 16; ++k2) {
      float cnt = red2[k2];
      if (cnt > 0.0f) {
        np += 1.0f;
        float ssg = red2[48+k2];
        float var = (red2[64+k2] - ssg*ssg/cnt) / cnt;
        if (var < 0.0f) var = 0.0f;
        vs += (double)var;
      }
    }
    double* ab = accd + (size_t)b*ACC_STRIDE;
    ab[80] = (double)red2[80];
    ab[81] = 0.0;
    ab[82] = 0.0;
    ab[83] = vs;
    ab[84] = np > 1.0f ? (double)np : 1.0;
  }
}

// ---------- pass 2: histograms (8 instances/block, z-binned negatives: no exp) ----------
__global__ __launch_bounds__(1024) void k_hist(const u64* __restrict__ rec,
    const float* __restrict__ pairinfo,
    unsigned* __restrict__ partial, double* __restrict__ accd)
{
  __shared__ unsigned hist[8*NB];   // 32 KB, P<<16 at e-bin, Q at z-bin
  __shared__ float redf[16];
  int t = threadIdx.x, bid = blockIdx.x;
  int b = bid & 7;                  // XCD-local image
  int rr = bid >> 3;
  int g = rr & 1;                   // instance group
  int s = rr >> 1;                  // pixel split 0..31
  for (int i = t; i < 8*NB; i += 1024) hist[i] = 0u;
  float cx[8], cy[8], se[8], s128[8];
  #pragma unroll
  for (int j = 0; j < 8; ++j) {
    float4 pi = ((const float4*)pairinfo)[b*16 + g*8 + j];
    cx[j] = pi.x; cy[j] = pi.y; se[j] = pi.z; s128[j] = pi.z * ((float)NB/ZMAX);
  }
  __syncthreads();
  size_t base = (size_t)b*HWPX + (size_t)s*(HWPX/NSPLIT);
  float fit = 0.0f;
  for (int it = 0; it < HWPX/NSPLIT/2048; ++it) {   // 4 iterations, 2 px each
    size_t px = base + it*2048 + t*2;
    ulonglong2 v2 = *((const ulonglong2*)(rec + px));
    u64 vv[2] = {v2.x, v2.y};
    #pragma unroll
    for (int c = 0; c < 2; ++c) {
      u64 v = vv[c];
      float ex = __half2float(__ushort_as_half((unsigned short)(v & 0xffffu)));
      float ey = __half2float(__ushort_as_half((unsigned short)((v >> 16) & 0xffffu)));
      float sd = __half2float(__ushort_as_half((unsigned short)((v >> 32) & 0xffffu)));
      int rel = (int)(v >> 48) - 1 - g*8;
      #pragma unroll
      for (int j = 0; j < 8; ++j) {
        float dx = ex - cx[j], dy = ey - cy[j];
        float d2 = fmaf(dx, dx, dy*dy);
        int key; unsigned add;
        if (rel == j) {                       // positive (rare)
          float d = __expf(-d2 * se[j]);
          float e = fmaf(-2.0f, d, 2.0f);
          int kk = (int)(e * (float)(NB/2));
          key = kk > NB-1 ? NB-1 : kk;
          add = 0x10000u;
          float df = sd - d; fit += df*df;
        } else {                              // negative: z-bin, no exp
          key = (int)fminf(d2 * s128[j], (float)(NB-1));
          add = 1u;
        }
        atomicAdd(&hist[j*NB + key], add);
      }
    }
  }
  #pragma unroll
  for (int o = 32; o > 0; o >>= 1) fit += __shfl_down(fit, o);
  if ((t & 63) == 0) redf[t >> 6] = fit;
  __syncthreads();
  if (t == 0) {
    float ft = 0.0f;
    for (int i = 0; i < 16; ++i) ft += redf[i];
    atomicAdd(&accd[(size_t)b*ACC_STRIDE + 81], (double)ft);
  }
  unsigned* pp = partial + (size_t)((b*NGRP + g)*NSPLIT + s)*(8*NB);
  for (int i = t; i < 8*NB; i += 1024) pp[i] = hist[i];
}

// ---------- pass 3: merge partials, z->e, descending scan + Lovasz integral ----------
__global__ __launch_bounds__(1024) void k_scan(const unsigned* __restrict__ partial,
    const float* __restrict__ pairinfo, double* __restrict__ accd)
{
  __shared__ unsigned sp[NB], sq[NB];
  __shared__ float red[16];
  int t = threadIdx.x, bid = blockIdx.x;
  int b = bid >> 4, k = bid & 15;
  int g = k >> 3, j8 = k & 7;
  float G = pairinfo[(b*16 + k)*4 + 3];
  if (G <= 0.0f) return;   // absent instance (uniform block exit)
  sq[t] = 0u;
  __syncthreads();
  unsigned p = 0, q = 0;
  const unsigned* basep = partial + (size_t)((b*NGRP + g)*NSPLIT)*(8*NB) + j8*NB + t;
  #pragma unroll 4
  for (int s2 = 0; s2 < NSPLIT; ++s2) {
    unsigned h = basep[(size_t)s2*(8*NB)];
    p += h >> 16; q += h & 0xffffu;
  }
  // q is a z-bin count: convert to e-bin (e = 2*exp(-z_mid))
  float zmid = (t + 0.5f) * (ZMAX/NB);
  float ev = 2.0f * __expf(-zmid);
  int eb = (int)(ev * (float)(NB/2));
  if (eb > NB-1) eb = NB-1;
  if (q) atomicAdd(&sq[eb], q);
  __syncthreads();
  unsigned qe = sq[t];
  __syncthreads();
  int j = (NB-1) - t;          // descending-e rank
  sp[j] = p; sq[j] = qe;
  __syncthreads();
  for (int off = 1; off < NB; off <<= 1) {
    unsigned vp = 0, vq = 0;
    if (j >= off) { vp = sp[j-off]; vq = sq[j-off]; }
    __syncthreads();
    sp[j] += vp; sq[j] += vq;
    __syncthreads();
  }
  float A  = (float)(sp[j] - p);    // positives strictly above my e-bin
  float Bn = (float)(sq[j] - qe);   // negatives strictly above my e-bin
  float val = (t + 0.5f) * (2.0f/NB);
  float pf = (float)p, qf = (float)qe;
  float Jb = (A + Bn) / (G + Bn);
  float Ja = (A + Bn + pf + qf) / (G + Bn + qf);
  float contrib = val * (Ja - Jb);
  #pragma unroll
  for (int o = 32; o > 0; o >>= 1) contrib += __shfl_down(contrib, o);
  if ((t & 63) == 0) red[t >> 6] = contrib;
  __syncthreads();
  if (t == 0) {
    float tot = 0.0f;
    for (int i = 0; i < 16; ++i) tot += red[i];
    atomicAdd(&accd[(size_t)b*ACC_STRIDE + 82], (double)tot);
  }
}

// ---------- fallback: proven round-1 kernel (recompute path, SHIFT=18) ----------
__global__ __launch_bounds__(1024) void k_lov_old(const float* __restrict__ pred,
    const int* __restrict__ inst, const int* __restrict__ lab,
    const float* __restrict__ pairinfo, double* __restrict__ accd)
{
  constexpr int SHIFT = 18;
  constexpr int NBB = (0x40000000 >> SHIFT) + 1;
  extern __shared__ unsigned char smem[];
  unsigned* histP = reinterpret_cast<unsigned*>(smem);
  unsigned* histQ = histP + NBB;
  unsigned* scanP = histQ + NBB;
  unsigned* scanQ = scanP + 1024;
  float* red  = reinterpret_cast<float*>(scanQ + 1024);
  float* redf = red + 16;
  int t = threadIdx.x, bid = blockIdx.x;
  int b = bid >> 4, k = bid & 15;
  float4 pi = reinterpret_cast<const float4*>(pairinfo)[bid];
  float cx = pi.x, cy = pi.y, sexp = pi.z, G = pi.w;
  if (G <= 0.0f) return;
  for (int i = t; i < 2*NBB; i += 1024) histP[i] = 0u;
  __syncthreads();
  size_t ib = (size_t)b * HWPX;
  const float* pb = pred + (size_t)b * 4 * HWPX;
  const int target = k + 1;
  float fit = 0.0f;
  for (int j = 0; j < HWPX/1024; ++j) {
    int px = (j << 10) + t;
    int h = px >> 9, w = px & 511;
    float ex = tanhf(pb[px]) + w*(1.0f/1023.0f);
    float ey = tanhf(pb[HWPX+px]) + h*(1.0f/1023.0f);
    float sd = 1.0f/(1.0f + __expf(-pb[3*HWPX+px]));
    int lv = lab[ib+px], iv = inst[ib+px];
    float dx = ex - cx, dy = ey - cy;
    float d = __expf(-sexp * (dx*dx + dy*dy));
    bool m = (lv == 1) && (iv == target);
    float e = m ? fmaf(-2.0f, d, 2.0f) : 2.0f * d;
    unsigned key = __float_as_uint(e) >> SHIFT;
    atomicAdd(m ? &histP[key] : &histQ[key], 1u);
    if (m) { float df = sd - d; fit += df*df; }
  }
  #pragma unroll
  for (int o = 32; o > 0; o >>= 1) fit += __shfl_down(fit, o);
  if ((t & 63) == 0) redf[t >> 6] = fit;
  __syncthreads();
  constexpr int CB = NBB / 1024;
  int start = (NBB - 1) - t * CB;
  int nk = (t == 1023) ? (CB + 1) : CB;
  unsigned lp = 0, lq = 0;
  for (int i = 0; i < nk; ++i) { lp += histP[start-i]; lq += histQ[start-i]; }
  scanP[t] = lp; scanQ[t] = lq;
  __syncthreads();
  for (int off = 1; off < 1024; off <<= 1) {
    unsigned vp = 0, vq = 0;
    if (t >= off) { vp = scanP[t-off]; vq = scanQ[t-off]; }
    __syncthreads();
    scanP[t] += vp; scanQ[t] += vq;
    __syncthreads();
  }
  float A  = (float)(scanP[t] - lp);
  float Bn = (float)(scanQ[t] - lq);
  float contrib = 0.0f;
  for (int i = 0; i < nk; ++i) {
    int kk = start - i;
    unsigned p = histP[kk], q = histQ[kk];
    if (p | q) {
      float lo = __uint_as_float((unsigned)kk << SHIFT);
      float hi = __uint_as_float((unsigned)(kk+1) << SHIFT);
      float valv = 0.5f*(lo+hi);
      if (valv > 2.0f) valv = 2.0f;
      float pq = (float)(p + q), qf = (float)q;
      float Jb = (A + Bn) / (G + Bn);
      float Ja = (A + Bn + pq) / (G + Bn + qf);
      contrib += valv * (Ja - Jb);
      A += (float)p; Bn += qf;
    }
  }
  #pragma unroll
  for (int o = 32; o > 0; o >>= 1) contrib += __shfl_down(contrib, o);
  if ((t & 63) == 0) red[t >> 6] = contrib;
  __syncthreads();
  if (t == 0) {
    float tot = 0.0f, ft = 0.0f;
    for (int i = 0; i < 16; ++i) { tot += red[i]; ft += redf[i]; }
    atomicAdd(&accd[(size_t)b*ACC_STRIDE + 82], (double)tot);
    atomicAdd(&accd[(size_t)b*ACC_STRIDE + 81], (double)ft);
  }
}

__global__ void k_final(const double* __restrict__ accd, float* __restrict__ out)
{
  int t = threadIdx.x;
  double lb = 0.0;
  if (t < NIMG) {
    const double* ab = accd + (size_t)t*ACC_STRIDE;
    lb = (ab[82] + 10.0*ab[83]) / ab[84] + (ab[80] + ab[81]) * (1.0/(double)HWPX);
  }
  #pragma unroll
  for (int o = 4; o > 0; o >>= 1) lb += __shfl_down(lb, o);
  if (t == 0) out[0] = (float)(lb * 0.125);
}

extern "C" void kernel_launch(void* const* d_in, const int* in_sizes, int n_in,
                              void* d_out, int out_size, void* d_ws, size_t ws_size,
                              hipStream_t stream)
{
  const float* pred = (const float*)d_in[0];
  const int*   inst = (const int*)d_in[1];
  const int*   lab  = (const int*)d_in[2];
  float* out = (float*)d_out;

  size_t recB   = (size_t)NIMG * HWPX * sizeof(u64);         // 16.78 MB
  size_t partB  = (size_t)NIMG * NGRP * NSPLIT * 8 * NB * 4; // 16.78 MB
  size_t pstatB = (size_t)STAT_GRID * 96 * sizeof(float);    //  0.79 MB
  size_t accB   = (size_t)NIMG * ACC_STRIDE * sizeof(double);
  size_t pairB  = 128 * 4 * sizeof(float);
  bool full = ws_size >= recB + partB + pstatB + accB + pairB;

  char* ws = (char*)d_ws;
  if (full) {
    u64*      rec   = (u64*)ws;
    unsigned* part  = (unsigned*)(ws + recB);
    float*    pstat = (float*)(ws + recB + partB);
    double*   accd  = (double*)(ws + recB + partB + pstatB);
    float*    pairinfo = (float*)(ws + recB + partB + pstatB + accB);
    k_stats<true><<<STAT_GRID,256,0,stream>>>(pred, inst, lab, rec, pstat);
    k_fin<<<NIMG,1024,0,stream>>>(pstat, accd, pairinfo);
    k_hist<<<NIMG*NGRP*NSPLIT,1024,0,stream>>>(rec, pairinfo, part, accd);
    k_scan<<<128,1024,0,stream>>>(part, pairinfo, accd);
    k_final<<<1,64,0,stream>>>(accd, out);
  } else {
    float*    pstat = (float*)ws;
    double*   accd  = (double*)(ws + pstatB);
    float*    pairinfo = (float*)(ws + pstatB + accB);
    k_stats<false><<<STAT_GRID,256,0,stream>>>(pred, inst, lab, nullptr, pstat);
    k_fin<<<NIMG,1024,0,stream>>>(pstat, accd, pairinfo);
    size_t lds18 = ((size_t)2*4097 + 2048)*4 + 128;
    k_lov_old<<<128,1024,lds18,stream>>>(pred, inst, lab, pairinfo, accd);
    k_final<<<1,64,0,stream>>>(accd, out);
  }
}

// Round 9
// 79.360 us; speedup vs baseline: 1.2004x; 1.2004x over previous
//
#include <hip/hip_runtime.h>
#include <math.h>

#define HWPX 262144   // 512*512
#define NIMG 8
#define ACC_STRIDE 96
#define NB 256        // histogram bins (e-space for P, z-space for Q)
#define ZMAX 8.0f
#define NSPLIT 64
#define STAT_GRID 2048   // 256 blocks/image, 1024 px/block, 4 px/thread
// accd layout per image (doubles):
// [80] bg_seed(acc), [81] fit_seed(acc), [82] inst_loss(acc), [83] var_loss, [84] obj

typedef unsigned long long u64;

__device__ __forceinline__ float tanh_fast(float x) {
  float t = __expf(2.0f * x);
  return 1.0f - __fdividef(2.0f, t + 1.0f);
}
__device__ __forceinline__ float sigmoid_fast(float x) {
  return __fdividef(1.0f, 1.0f + __expf(-x));
}

// ---------- pass 1: stats partials. Reads ONLY sigma/lab/inst (12 B/px). ----------
__global__ __launch_bounds__(256) void k_stats(const float* __restrict__ pred,
    const int* __restrict__ inst, const int* __restrict__ lab,
    float* __restrict__ part)
{
  __shared__ float s[8][83];   // 8 replicas, stride 83 (coprime with 32 banks)
  int t = threadIdx.x;
  for (int i = t; i < 8*83; i += 256) (&s[0][0])[i] = 0.0f;
  __syncthreads();
  int bid = blockIdx.x;
  int b = bid >> 8;                       // 256 blocks per image
  int px0 = ((bid & 255) << 10) + t*4;    // 4 consecutive px per thread (same row)
  const float* pb = pred + (size_t)b*4*HWPX;
  size_t ib = (size_t)b*HWPX;
  int r = t & 7;
  int w0 = px0 & 511;
  float ym = (float)(px0 >> 9) * (1.0f/1023.0f);

  float4 Gv = *(const float4*)(pb + 2*HWPX + px0);
  int4   L  = *(const int4*)(lab + ib + px0);
  int4   I  = *(const int4*)(inst + ib + px0);

#define PXS(C, GG, LL, II) { \
    int mid = ((LL) == 1 && (unsigned)((II)-1) < 16u) ? (II) : 0; \
    if (mid) { int k = mid - 1; \
      float xm = (float)(w0 + C) * (1.0f/1023.0f); \
      atomicAdd(&s[r][k], 1.0f); \
      atomicAdd(&s[r][16+k], xm); \
      atomicAdd(&s[r][32+k], ym); \
      atomicAdd(&s[r][48+k], GG); \
      atomicAdd(&s[r][64+k], (GG)*(GG)); } }
  PXS(0, Gv.x, L.x, I.x)
  PXS(1, Gv.y, L.y, I.y)
  PXS(2, Gv.z, L.z, I.z)
  PXS(3, Gv.w, L.w, I.w)
#undef PXS

  __syncthreads();
  if (t < 96) {
    float v = 0.0f;
    if (t < 80) {
      #pragma unroll
      for (int rr = 0; rr < 8; ++rr) v += s[rr][t];
    }
    part[(size_t)bid*96 + t] = v;
  }
}

// ---------- pass 1b: reduce partials, finalize pairinfo + accd, zero P/Q hists ----------
__global__ __launch_bounds__(1024) void k_fin(const float* __restrict__ part,
    double* __restrict__ accd, float* __restrict__ pairinfo,
    unsigned* __restrict__ Pg, unsigned* __restrict__ Qg)
{
  __shared__ float red2[10*96];
  int t = threadIdx.x, b = blockIdx.x;
  // zero this image's global histograms (16 inst * NB bins, P and Q)
  for (int i = t; i < 16*NB; i += 1024) {
    Pg[b*16*NB + i] = 0u;
    Qg[b*16*NB + i] = 0u;
  }
  if (t < 960) {
    int e = t % 96, c = t / 96;
    int lo = c*26, hi = lo + 26; if (hi > 256) hi = 256;
    const float* pp = part + (size_t)b*256*96 + e;
    float v = 0.0f;
    for (int blk = lo; blk < hi; ++blk) v += pp[(size_t)blk*96];
    red2[c*96 + e] = v;
  }
  __syncthreads();
  if (t < 96) {
    float v = 0.0f;
    #pragma unroll
    for (int cc = 0; cc < 10; ++cc) v += red2[cc*96 + t];
    red2[t] = v;
  }
  __syncthreads();
  if (t < 16) {
    float cnt = red2[t];
    float safe = cnt > 0.0f ? cnt : 1.0f;
    float sm = red2[48+t] / safe;
    float4 pi = make_float4(red2[16+t]/safe, red2[32+t]/safe, __expf(10.0f*sm), cnt);
    ((float4*)pairinfo)[b*16 + t] = pi;
  }
  if (t == 0) {
    double vs = 0.0; float np = 0.0f;
    for (int k2 = 0; k2 < 16; ++k2) {
      float cnt = red2[k2];
      if (cnt > 0.0f) {
        np += 1.0f;
        float ssg = red2[48+k2];
        float var = (red2[64+k2] - ssg*ssg/cnt) / cnt;
        if (var < 0.0f) var = 0.0f;
        vs += (double)var;
      }
    }
    double* ab = accd + (size_t)b*ACC_STRIDE;
    ab[80] = 0.0;
    ab[81] = 0.0;
    ab[82] = 0.0;
    ab[83] = vs;
    ab[84] = np > 1.0f ? (double)np : 1.0;
  }
}

// ---------- pass 2: 16-inst histograms from raw inputs; merge via global atomics ----------
__global__ __launch_bounds__(1024) void k_hist(const float* __restrict__ pred,
    const int* __restrict__ inst, const int* __restrict__ lab,
    const float* __restrict__ pairinfo,
    unsigned* __restrict__ Pg, unsigned* __restrict__ Qg, double* __restrict__ accd)
{
  __shared__ unsigned hist[16*NB];   // 16 KB: P<<16 at e-bin, Q at z-bin
  __shared__ float redf[16], redb[16];
  int t = threadIdx.x, bid = blockIdx.x;
  int b = bid & 7;                  // XCD-local image
  int s = bid >> 3;                 // pixel split 0..63
  for (int i = t; i < 16*NB; i += 1024) hist[i] = 0u;
  float cx[16], cy[16], s128[16];
  #pragma unroll
  for (int j = 0; j < 16; ++j) {
    float4 pi = ((const float4*)pairinfo)[b*16 + j];
    cx[j] = pi.x; cy[j] = pi.y; s128[j] = pi.z * ((float)NB/ZMAX);
  }
  __syncthreads();
  int px0 = s*(HWPX/NSPLIT) + t*4;   // 4096 px per split
  const float* pb = pred + (size_t)b*4*HWPX;
  size_t ib = (size_t)b*HWPX;
  float4 X = *(const float4*)(pb + px0);
  float4 Y = *(const float4*)(pb + HWPX + px0);
  float4 Q = *(const float4*)(pb + 3*HWPX + px0);
  int4   L = *(const int4*)(lab + ib + px0);
  int4   I = *(const int4*)(inst + ib + px0);
  int w0 = px0 & 511;
  float ym = (float)(px0 >> 9) * (1.0f/1023.0f);
  float fit = 0.0f, bg = 0.0f;

#define PXH(C, XX, YY, QQ, LL, II) { \
    float xm = (float)(w0 + C) * (1.0f/1023.0f); \
    float exf = tanh_fast(XX) + xm; \
    float eyf = tanh_fast(YY) + ym; \
    float sd = sigmoid_fast(QQ); \
    int rel = ((LL) == 1 && (unsigned)((II)-1) < 16u) ? ((II)-1) : -1; \
    bg += ((LL) == 0) ? sd*sd : 0.0f; \
    _Pragma("unroll") \
    for (int j = 0; j < 16; ++j) { \
      float dx = exf - cx[j], dy = eyf - cy[j]; \
      float z = fmaf(dx, dx, dy*dy) * s128[j]; \
      int key; unsigned add; \
      if (j == rel) { \
        float d = __expf(-z * (ZMAX/(float)NB)); \
        float e = fmaf(-2.0f, d, 2.0f); \
        int kp = (int)(e * (float)(NB/2)); key = kp > NB-1 ? NB-1 : kp; \
        add = 0x10000u; \
        float df = sd - d; fit += df*df; \
      } else { \
        key = (int)fminf(z, (float)(NB-1)); \
        add = 1u; \
      } \
      atomicAdd(&hist[j*NB + key], add); \
    } }
  PXH(0, X.x, Y.x, Q.x, L.x, I.x)
  PXH(1, X.y, Y.y, Q.y, L.y, I.y)
  PXH(2, X.z, Y.z, Q.z, L.z, I.z)
  PXH(3, X.w, Y.w, Q.w, L.w, I.w)
#undef PXH

  #pragma unroll
  for (int o = 32; o > 0; o >>= 1) { fit += __shfl_down(fit, o); bg += __shfl_down(bg, o); }
  if ((t & 63) == 0) { redf[t >> 6] = fit; redb[t >> 6] = bg; }
  __syncthreads();
  if (t == 0) {
    float ft = 0.0f, bt = 0.0f;
    for (int i = 0; i < 16; ++i) { ft += redf[i]; bt += redb[i]; }
    atomicAdd(&accd[(size_t)b*ACC_STRIDE + 81], (double)ft);
    atomicAdd(&accd[(size_t)b*ACC_STRIDE + 80], (double)bt);
  }
  // merge LDS histograms into per-image global hists (sparse-guarded)
  for (int i = t; i < 16*NB; i += 1024) {
    unsigned h = hist[i];
    if (h) {
      unsigned hp = h >> 16, hq = h & 0xffffu;
      if (hp) atomicAdd(&Pg[b*16*NB + i], hp);
      if (hq) atomicAdd(&Qg[b*16*NB + i], hq);
    }
  }
}

// ---------- pass 3: z->e conversion, descending scan + Lovasz integral ----------
__global__ __launch_bounds__(NB) void k_scan(const unsigned* __restrict__ Pg,
    const unsigned* __restrict__ Qg,
    const float* __restrict__ pairinfo, double* __restrict__ accd)
{
  __shared__ unsigned sp[NB], sq[NB];
  __shared__ float red[4];
  int t = threadIdx.x, bid = blockIdx.x;
  int b = bid >> 4, k = bid & 15;
  float G = pairinfo[(b*16 + k)*4 + 3];
  if (G <= 0.0f) return;   // absent instance (uniform block exit)
  sq[t] = 0u;
  __syncthreads();
  unsigned p = Pg[(b*16 + k)*NB + t];
  unsigned q = Qg[(b*16 + k)*NB + t];
  // q is a z-bin count: convert to e-bin (e = 2*exp(-z_mid))
  float zmid = (t + 0.5f) * (ZMAX/NB);
  float ev = 2.0f * __expf(-zmid);
  int eb = (int)(ev * (float)(NB/2));
  if (eb > NB-1) eb = NB-1;
  if (q) atomicAdd(&sq[eb], q);
  __syncthreads();
  unsigned qe = sq[t];
  __syncthreads();
  int j = (NB-1) - t;          // descending-e rank
  sp[j] = p; sq[j] = qe;
  __syncthreads();
  for (int off = 1; off < NB; off <<= 1) {
    unsigned vp = 0, vq = 0;
    if (j >= off) { vp = sp[j-off]; vq = sq[j-off]; }
    __syncthreads();
    sp[j] += vp; sq[j] += vq;
    __syncthreads();
  }
  float A  = (float)(sp[j] - p);    // positives strictly above my e-bin
  float Bn = (float)(sq[j] - qe);   // negatives strictly above my e-bin
  float val = (t + 0.5f) * (2.0f/NB);
  float pf = (float)p, qf = (float)qe;
  float Jb = (A + Bn) / (G + Bn);
  float Ja = (A + Bn + pf + qf) / (G + Bn + qf);
  float contrib = val * (Ja - Jb);
  #pragma unroll
  for (int o = 32; o > 0; o >>= 1) contrib += __shfl_down(contrib, o);
  if ((t & 63) == 0) red[t >> 6] = contrib;
  __syncthreads();
  if (t == 0) {
    float tot = red[0] + red[1] + red[2] + red[3];
    atomicAdd(&accd[(size_t)b*ACC_STRIDE + 82], (double)tot);
  }
}

__global__ void k_final(const double* __restrict__ accd, float* __restrict__ out)
{
  int t = threadIdx.x;
  double lb = 0.0;
  if (t < NIMG) {
    const double* ab = accd + (size_t)t*ACC_STRIDE;
    lb = (ab[82] + 10.0*ab[83]) / ab[84] + (ab[80] + ab[81]) * (1.0/(double)HWPX);
  }
  #pragma unroll
  for (int o = 4; o > 0; o >>= 1) lb += __shfl_down(lb, o);
  if (t == 0) out[0] = (float)(lb * 0.125);
}

// ---------- fallback helpers (exercised only if ws is tiny; main path needs ~2 MB) ----------
__global__ __launch_bounds__(256) void k_bg(const float* __restrict__ pred,
    const int* __restrict__ lab, double* __restrict__ accd)
{
  __shared__ float redb[4];
  int t = threadIdx.x, bid = blockIdx.x;
  int b = bid >> 8;
  int px0 = ((bid & 255) << 10) + t*4;
  const float* pb = pred + (size_t)b*4*HWPX;
  size_t ib = (size_t)b*HWPX;
  float4 Q = *(const float4*)(pb + 3*HWPX + px0);
  int4   L = *(const int4*)(lab + ib + px0);
  float bg = 0.0f;
  float qs[4] = {Q.x,Q.y,Q.z,Q.w};
  int   ls[4] = {L.x,L.y,L.z,L.w};
  #pragma unroll
  for (int c = 0; c < 4; ++c) {
    float sd = sigmoid_fast(qs[c]);
    bg += (ls[c] == 0) ? sd*sd : 0.0f;
  }
  #pragma unroll
  for (int o = 32; o > 0; o >>= 1) bg += __shfl_down(bg, o);
  if ((t & 63) == 0) redb[t >> 6] = bg;
  __syncthreads();
  if (t == 0) atomicAdd(&accd[(size_t)b*ACC_STRIDE + 80],
                        (double)(redb[0]+redb[1]+redb[2]+redb[3]));
}

__global__ __launch_bounds__(1024) void k_lov_old(const float* __restrict__ pred,
    const int* __restrict__ inst, const int* __restrict__ lab,
    const float* __restrict__ pairinfo, double* __restrict__ accd)
{
  constexpr int SHIFT = 18;
  constexpr int NBB = (0x40000000 >> SHIFT) + 1;
  extern __shared__ unsigned char smem[];
  unsigned* histP = reinterpret_cast<unsigned*>(smem);
  unsigned* histQ = histP + NBB;
  unsigned* scanP = histQ + NBB;
  unsigned* scanQ = scanP + 1024;
  float* red  = reinterpret_cast<float*>(scanQ + 1024);
  float* redf = red + 16;
  int t = threadIdx.x, bid = blockIdx.x;
  int b = bid >> 4, k = bid & 15;
  float4 pi = reinterpret_cast<const float4*>(pairinfo)[bid];
  float cx = pi.x, cy = pi.y, sexp = pi.z, G = pi.w;
  if (G <= 0.0f) return;
  for (int i = t; i < 2*NBB; i += 1024) histP[i] = 0u;
  __syncthreads();
  size_t ib = (size_t)b * HWPX;
  const float* pb = pred + (size_t)b * 4 * HWPX;
  const int target = k + 1;
  float fit = 0.0f;
  for (int j = 0; j < HWPX/1024; ++j) {
    int px = (j << 10) + t;
    int h = px >> 9, w = px & 511;
    float ex = tanhf(pb[px]) + w*(1.0f/1023.0f);
    float ey = tanhf(pb[HWPX+px]) + h*(1.0f/1023.0f);
    float sd = 1.0f/(1.0f + __expf(-pb[3*HWPX+px]));
    int lv = lab[ib+px], iv = inst[ib+px];
    float dx = ex - cx, dy = ey - cy;
    float d = __expf(-sexp * (dx*dx + dy*dy));
    bool m = (lv == 1) && (iv == target);
    float e = m ? fmaf(-2.0f, d, 2.0f) : 2.0f * d;
    unsigned key = __float_as_uint(e) >> SHIFT;
    atomicAdd(m ? &histP[key] : &histQ[key], 1u);
    if (m) { float df = sd - d; fit += df*df; }
  }
  #pragma unroll
  for (int o = 32; o > 0; o >>= 1) fit += __shfl_down(fit, o);
  if ((t & 63) == 0) redf[t >> 6] = fit;
  __syncthreads();
  constexpr int CB = NBB / 1024;
  int start = (NBB - 1) - t * CB;
  int nk = (t == 1023) ? (CB + 1) : CB;
  unsigned lp = 0, lq = 0;
  for (int i = 0; i < nk; ++i) { lp += histP[start-i]; lq += histQ[start-i]; }
  scanP[t] = lp; scanQ[t] = lq;
  __syncthreads();
  for (int off = 1; off < 1024; off <<= 1) {
    unsigned vp = 0, vq = 0;
    if (t >= off) { vp = scanP[t-off]; vq = scanQ[t-off]; }
    __syncthreads();
    scanP[t] += vp; scanQ[t] += vq;
    __syncthreads();
  }
  float A  = (float)(scanP[t] - lp);
  float Bn = (float)(scanQ[t] - lq);
  float contrib = 0.0f;
  for (int i = 0; i < nk; ++i) {
    int kk = start - i;
    unsigned p = histP[kk], q = histQ[kk];
    if (p | q) {
      float lo = __uint_as_float((unsigned)kk << SHIFT);
      float hi = __uint_as_float((unsigned)(kk+1) << SHIFT);
      float valv = 0.5f*(lo+hi);
      if (valv > 2.0f) valv = 2.0f;
      float pq = (float)(p + q), qf = (float)q;
      float Jb = (A + Bn) / (G + Bn);
      float Ja = (A + Bn + pq) / (G + Bn + qf);
      contrib += valv * (Ja - Jb);
      A += (float)p; Bn += qf;
    }
  }
  #pragma unroll
  for (int o = 32; o > 0; o >>= 1) contrib += __shfl_down(contrib, o);
  if ((t & 63) == 0) red[t >> 6] = contrib;
  __syncthreads();
  if (t == 0) {
    float tot = 0.0f, ft = 0.0f;
    for (int i = 0; i < 16; ++i) { tot += red[i]; ft += redf[i]; }
    atomicAdd(&accd[(size_t)b*ACC_STRIDE + 82], (double)tot);
    atomicAdd(&accd[(size_t)b*ACC_STRIDE + 81], (double)ft);
  }
}

extern "C" void kernel_launch(void* const* d_in, const int* in_sizes, int n_in,
                              void* d_out, int out_size, void* d_ws, size_t ws_size,
                              hipStream_t stream)
{
  const float* pred = (const float*)d_in[0];
  const int*   inst = (const int*)d_in[1];
  const int*   lab  = (const int*)d_in[2];
  float* out = (float*)d_out;

  size_t pqB    = (size_t)NIMG * 16 * NB * 4;                // 128 KB each
  size_t pstatB = (size_t)STAT_GRID * 96 * sizeof(float);    // 786 KB
  size_t accB   = (size_t)NIMG * ACC_STRIDE * sizeof(double);
  size_t pairB  = 128 * 4 * sizeof(float);
  bool full = ws_size >= 2*pqB + pstatB + accB + pairB;

  char* ws = (char*)d_ws;
  if (full) {
    unsigned* Pg    = (unsigned*)ws;
    unsigned* Qg    = (unsigned*)(ws + pqB);
    float*    pstat = (float*)(ws + 2*pqB);
    double*   accd  = (double*)(ws + 2*pqB + pstatB);
    float*    pairinfo = (float*)(ws + 2*pqB + pstatB + accB);
    k_stats<<<STAT_GRID,256,0,stream>>>(pred, inst, lab, pstat);
    k_fin<<<NIMG,1024,0,stream>>>(pstat, accd, pairinfo, Pg, Qg);
    k_hist<<<NIMG*NSPLIT,1024,0,stream>>>(pred, inst, lab, pairinfo, Pg, Qg, accd);
    k_scan<<<128,NB,0,stream>>>(Pg, Qg, pairinfo, accd);
    k_final<<<1,64,0,stream>>>(accd, out);
  } else {
    // tiny-ws fallback (not expected to trigger): stats+bg+old single-instance kernel
    float*    pstat = (float*)ws;
    double*   accd  = (double*)(ws + pstatB);
    float*    pairinfo = (float*)(ws + pstatB + accB);
    unsigned* Pg = (unsigned*)(ws + pstatB + accB + pairB);   // dummy zero targets
    unsigned* Qg = Pg + NIMG*16*NB;
    k_stats<<<STAT_GRID,256,0,stream>>>(pred, inst, lab, pstat);
    k_fin<<<NIMG,1024,0,stream>>>(pstat, accd, pairinfo, Pg, Qg);
    k_bg<<<STAT_GRID,256,0,stream>>>(pred, lab, accd);
    size_t lds18 = ((size_t)2*4097 + 2048)*4 + 128;
    k_lov_old<<<128,1024,lds18,stream>>>(pred, inst, lab, pairinfo, accd);
    k_final<<<1,64,0,stream>>>(accd, out);
  }
}

// Round 10
// 65.502 us; speedup vs baseline: 1.4544x; 1.2116x over previous
//
#include <hip/hip_runtime.h>
#include <hip/hip_fp16.h>
#include <math.h>

#define HWPX 262144   // 512*512
#define NIMG 8
#define ACC_STRIDE 96
#define NB 1024       // histogram bins (e-space for P, z-space for Q)
#define ZMAX 8.0f
#define NSPLIT 16
#define NGRP 2
#define PREP_BLOCKS 256   // 32 blocks/image, 1024 thr, 8 iterations x 1 px scalar
// accd layout per image (doubles):
// [80] bg_seed, [81] fit_seed(acc), [82] inst_loss(acc), [83] var_loss, [84] obj

typedef unsigned long long u64;

__device__ __forceinline__ float tanh_fast(float x) {
  float t = __expf(2.0f * x);
  return 1.0f - __fdividef(2.0f, t + 1.0f);
}
__device__ __forceinline__ float sigmoid_fast(float x) {
  return __fdividef(1.0f, 1.0f + __expf(-x));
}

// ---------- pass 1: k_lov-shaped streaming (1024 thr, scalar loads, 8-iter loop) ----------
template<bool PACK>
__global__ __launch_bounds__(1024) void k_prep(const float* __restrict__ pred,
    const int* __restrict__ inst, const int* __restrict__ lab,
    u64* __restrict__ rec, float* __restrict__ part)
{
  __shared__ float s[8][83];   // 8 replicas, stride 83 (coprime with 32 banks)
  int t = threadIdx.x;
  for (int i = t; i < 8*83; i += 1024) (&s[0][0])[i] = 0.0f;
  __syncthreads();
  int bid = blockIdx.x;
  int b = bid >> 5;                 // 32 blocks per image
  int chunk = bid & 31;             // 8192 px per block
  const float* pb = pred + (size_t)b*4*HWPX;
  size_t ib = (size_t)b*HWPX;
  int r = t & 7;
  float bg = 0.0f;
  #pragma unroll
  for (int j = 0; j < 8; ++j) {
    int px = (chunk << 13) + (j << 10) + t;
    float X = pb[px];
    float Y = pb[HWPX + px];
    float Gv = pb[2*HWPX + px];
    float Q = pb[3*HWPX + px];
    int L = lab[ib + px];
    int I = inst[ib + px];
    int w = px & 511, h = px >> 9;
    float xm = (float)w * (1.0f/1023.0f), ym = (float)h * (1.0f/1023.0f);
    float sd = sigmoid_fast(Q);
    int mid = (L == 1 && (unsigned)(I-1) < 16u) ? I : 0;
    if (PACK) {
      float ex = tanh_fast(X) + xm;
      float ey = tanh_fast(Y) + ym;
      rec[ib + px] = (u64)__half_as_ushort(__float2half(ex))
                   | ((u64)__half_as_ushort(__float2half(ey)) << 16)
                   | ((u64)__half_as_ushort(__float2half(sd)) << 32)
                   | ((u64)mid << 48);
    }
    if (L == 0) {
      bg += sd*sd;
    } else if (mid) {
      int k = mid - 1;
      atomicAdd(&s[r][k], 1.0f);
      atomicAdd(&s[r][16+k], xm);
      atomicAdd(&s[r][32+k], ym);
      atomicAdd(&s[r][48+k], Gv);
      atomicAdd(&s[r][64+k], Gv*Gv);
    }
  }
  #pragma unroll
  for (int o = 32; o > 0; o >>= 1) bg += __shfl_down(bg, o);
  if ((t & 63) == 0) atomicAdd(&s[0][80], bg);
  __syncthreads();
  if (t < 96) {
    float v = 0.0f;
    if (t < 81) {
      #pragma unroll
      for (int rr = 0; rr < 8; ++rr) v += s[rr][t];
    }
    part[(size_t)bid*96 + t] = v;
  }
}

// ---------- pass 1b: reduce 32 partials/image, finalize pairinfo + accd ----------
__global__ __launch_bounds__(128) void k_fin(const float* __restrict__ part,
    double* __restrict__ accd, float* __restrict__ pairinfo)
{
  __shared__ float red[96];
  int t = threadIdx.x, b = blockIdx.x;
  if (t < 96) {
    float v = 0.0f;
    const float* pp = part + (size_t)b*32*96 + t;
    #pragma unroll 8
    for (int blk = 0; blk < 32; ++blk) v += pp[(size_t)blk*96];
    red[t] = v;
  }
  __syncthreads();
  if (t < 16) {
    float cnt = red[t];
    float safe = cnt > 0.0f ? cnt : 1.0f;
    float sm = red[48+t] / safe;
    float4 pi = make_float4(red[16+t]/safe, red[32+t]/safe, __expf(10.0f*sm), cnt);
    ((float4*)pairinfo)[b*16 + t] = pi;
  }
  if (t == 0) {
    double vs = 0.0; float np = 0.0f;
    for (int k2 = 0; k2 < 16; ++k2) {
      float cnt = red[k2];
      if (cnt > 0.0f) {
        np += 1.0f;
        float ssg = red[48+k2];
        float var = (red[64+k2] - ssg*ssg/cnt) / cnt;
        if (var < 0.0f) var = 0.0f;
        vs += (double)var;
      }
    }
    double* ab = accd + (size_t)b*ACC_STRIDE;
    ab[80] = (double)red[80];
    ab[81] = 0.0;
    ab[82] = 0.0;
    ab[83] = vs;
    ab[84] = np > 1.0f ? (double)np : 1.0;
  }
}

// ---------- pass 2: 8-inst histograms, scalar rec loads, 16-iter loop ----------
__global__ __launch_bounds__(1024) void k_hist(const u64* __restrict__ rec,
    const float* __restrict__ pairinfo,
    unsigned* __restrict__ partial, double* __restrict__ accd)
{
  __shared__ unsigned hist[8*NB];   // 32 KB, P<<16 at e-bin, Q at z-bin
  __shared__ float redf[16];
  int t = threadIdx.x, bid = blockIdx.x;
  int b = bid & 7;                  // XCD-local image
  int rr = bid >> 3;
  int g = rr & 1;                   // instance group
  int s = rr >> 1;                  // pixel split 0..15
  for (int i = t; i < 8*NB; i += 1024) hist[i] = 0u;
  float cx[8], cy[8], se[8], s128[8];
  #pragma unroll
  for (int j = 0; j < 8; ++j) {
    float4 pi = ((const float4*)pairinfo)[b*16 + g*8 + j];
    cx[j] = pi.x; cy[j] = pi.y; se[j] = pi.z; s128[j] = pi.z * ((float)NB/ZMAX);
  }
  __syncthreads();
  size_t base = (size_t)b*HWPX + (size_t)s*(HWPX/NSPLIT);
  float fit = 0.0f;
  #pragma unroll 2
  for (int it = 0; it < HWPX/NSPLIT/1024; ++it) {   // 16 iterations, scalar u64
    size_t px = base + it*1024 + t;
    u64 v = rec[px];
    float ex = __half2float(__ushort_as_half((unsigned short)(v & 0xffffu)));
    float ey = __half2float(__ushort_as_half((unsigned short)((v >> 16) & 0xffffu)));
    float sd = __half2float(__ushort_as_half((unsigned short)((v >> 32) & 0xffffu)));
    int rel = (int)(v >> 48) - 1 - g*8;
    #pragma unroll
    for (int j = 0; j < 8; ++j) {
      float dx = ex - cx[j], dy = ey - cy[j];
      float d2 = fmaf(dx, dx, dy*dy);
      int key; unsigned add;
      if (rel == j) {                       // positive (rare)
        float d = __expf(-d2 * se[j]);
        float e = fmaf(-2.0f, d, 2.0f);
        int kk = (int)(e * (float)(NB/2));
        key = kk > NB-1 ? NB-1 : kk;
        add = 0x10000u;
        float df = sd - d; fit += df*df;
      } else {                              // negative: z-bin, no exp
        key = (int)fminf(d2 * s128[j], (float)(NB-1));
        add = 1u;
      }
      atomicAdd(&hist[j*NB + key], add);
    }
  }
  #pragma unroll
  for (int o = 32; o > 0; o >>= 1) fit += __shfl_down(fit, o);
  if ((t & 63) == 0) redf[t >> 6] = fit;
  __syncthreads();
  if (t == 0) {
    float ft = 0.0f;
    for (int i = 0; i < 16; ++i) ft += redf[i];
    atomicAdd(&accd[(size_t)b*ACC_STRIDE + 81], (double)ft);
  }
  unsigned* pp = partial + (size_t)((b*NGRP + g)*NSPLIT + s)*(8*NB);
  for (int i = t; i < 8*NB; i += 1024) pp[i] = hist[i];
}

// ---------- pass 3: merge partials, z->e, descending scan + Lovasz integral ----------
__global__ __launch_bounds__(1024) void k_scan(const unsigned* __restrict__ partial,
    const float* __restrict__ pairinfo, double* __restrict__ accd)
{
  __shared__ unsigned sp[NB], sq[NB];
  __shared__ float red[16];
  int t = threadIdx.x, bid = blockIdx.x;
  int b = bid >> 4, k = bid & 15;
  int g = k >> 3, j8 = k & 7;
  float G = pairinfo[(b*16 + k)*4 + 3];
  if (G <= 0.0f) return;   // absent instance (uniform block exit)
  sq[t] = 0u;
  __syncthreads();
  unsigned p = 0, q = 0;
  const unsigned* basep = partial + (size_t)((b*NGRP + g)*NSPLIT)*(8*NB) + j8*NB + t;
  #pragma unroll 4
  for (int s2 = 0; s2 < NSPLIT; ++s2) {
    unsigned h = basep[(size_t)s2*(8*NB)];
    p += h >> 16; q += h & 0xffffu;
  }
  // q is a z-bin count: convert to e-bin (e = 2*exp(-z_mid))
  float zmid = (t + 0.5f) * (ZMAX/NB);
  float ev = 2.0f * __expf(-zmid);
  int eb = (int)(ev * (float)(NB/2));
  if (eb > NB-1) eb = NB-1;
  if (q) atomicAdd(&sq[eb], q);
  __syncthreads();
  unsigned qe = sq[t];
  __syncthreads();
  int j = (NB-1) - t;          // descending-e rank
  sp[j] = p; sq[j] = qe;
  __syncthreads();
  for (int off = 1; off < NB; off <<= 1) {
    unsigned vp = 0, vq = 0;
    if (j >= off) { vp = sp[j-off]; vq = sq[j-off]; }
    __syncthreads();
    sp[j] += vp; sq[j] += vq;
    __syncthreads();
  }
  float A  = (float)(sp[j] - p);    // positives strictly above my e-bin
  float Bn = (float)(sq[j] - qe);   // negatives strictly above my e-bin
  float val = (t + 0.5f) * (2.0f/NB);
  float pf = (float)p, qf = (float)qe;
  float Jb = (A + Bn) / (G + Bn);
  float Ja = (A + Bn + pf + qf) / (G + Bn + qf);
  float contrib = val * (Ja - Jb);
  #pragma unroll
  for (int o = 32; o > 0; o >>= 1) contrib += __shfl_down(contrib, o);
  if ((t & 63) == 0) red[t >> 6] = contrib;
  __syncthreads();
  if (t == 0) {
    float tot = 0.0f;
    for (int i = 0; i < 16; ++i) tot += red[i];
    atomicAdd(&accd[(size_t)b*ACC_STRIDE + 82], (double)tot);
  }
}

// ---------- fallback: proven round-1 kernel (recompute path, SHIFT=18) ----------
__global__ __launch_bounds__(1024) void k_lov_old(const float* __restrict__ pred,
    const int* __restrict__ inst, const int* __restrict__ lab,
    const float* __restrict__ pairinfo, double* __restrict__ accd)
{
  constexpr int SHIFT = 18;
  constexpr int NBB = (0x40000000 >> SHIFT) + 1;
  extern __shared__ unsigned char smem[];
  unsigned* histP = reinterpret_cast<unsigned*>(smem);
  unsigned* histQ = histP + NBB;
  unsigned* scanP = histQ + NBB;
  unsigned* scanQ = scanP + 1024;
  float* red  = reinterpret_cast<float*>(scanQ + 1024);
  float* redf = red + 16;
  int t = threadIdx.x, bid = blockIdx.x;
  int b = bid >> 4, k = bid & 15;
  float4 pi = reinterpret_cast<const float4*>(pairinfo)[bid];
  float cx = pi.x, cy = pi.y, sexp = pi.z, G = pi.w;
  if (G <= 0.0f) return;
  for (int i = t; i < 2*NBB; i += 1024) histP[i] = 0u;
  __syncthreads();
  size_t ib = (size_t)b * HWPX;
  const float* pb = pred + (size_t)b * 4 * HWPX;
  const int target = k + 1;
  float fit = 0.0f;
  for (int j = 0; j < HWPX/1024; ++j) {
    int px = (j << 10) + t;
    int h = px >> 9, w = px & 511;
    float ex = tanhf(pb[px]) + w*(1.0f/1023.0f);
    float ey = tanhf(pb[HWPX+px]) + h*(1.0f/1023.0f);
    float sd = 1.0f/(1.0f + __expf(-pb[3*HWPX+px]));
    int lv = lab[ib+px], iv = inst[ib+px];
    float dx = ex - cx, dy = ey - cy;
    float d = __expf(-sexp * (dx*dx + dy*dy));
    bool m = (lv == 1) && (iv == target);
    float e = m ? fmaf(-2.0f, d, 2.0f) : 2.0f * d;
    unsigned key = __float_as_uint(e) >> SHIFT;
    atomicAdd(m ? &histP[key] : &histQ[key], 1u);
    if (m) { float df = sd - d; fit += df*df; }
  }
  #pragma unroll
  for (int o = 32; o > 0; o >>= 1) fit += __shfl_down(fit, o);
  if ((t & 63) == 0) redf[t >> 6] = fit;
  __syncthreads();
  constexpr int CB = NBB / 1024;
  int start = (NBB - 1) - t * CB;
  int nk = (t == 1023) ? (CB + 1) : CB;
  unsigned lp = 0, lq = 0;
  for (int i = 0; i < nk; ++i) { lp += histP[start-i]; lq += histQ[start-i]; }
  scanP[t] = lp; scanQ[t] = lq;
  __syncthreads();
  for (int off = 1; off < 1024; off <<= 1) {
    unsigned vp = 0, vq = 0;
    if (t >= off) { vp = scanP[t-off]; vq = scanQ[t-off]; }
    __syncthreads();
    scanP[t] += vp; scanQ[t] += vq;
    __syncthreads();
  }
  float A  = (float)(scanP[t] - lp);
  float Bn = (float)(scanQ[t] - lq);
  float contrib = 0.0f;
  for (int i = 0; i < nk; ++i) {
    int kk = start - i;
    unsigned p = histP[kk], q = histQ[kk];
    if (p | q) {
      float lo = __uint_as_float((unsigned)kk << SHIFT);
      float hi = __uint_as_float((unsigned)(kk+1) << SHIFT);
      float valv = 0.5f*(lo+hi);
      if (valv > 2.0f) valv = 2.0f;
      float pq = (float)(p + q), qf = (float)q;
      float Jb = (A + Bn) / (G + Bn);
      float Ja = (A + Bn + pq) / (G + Bn + qf);
      contrib += valv * (Ja - Jb);
      A += (float)p; Bn += qf;
    }
  }
  #pragma unroll
  for (int o = 32; o > 0; o >>= 1) contrib += __shfl_down(contrib, o);
  if ((t & 63) == 0) red[t >> 6] = contrib;
  __syncthreads();
  if (t == 0) {
    float tot = 0.0f, ft = 0.0f;
    for (int i = 0; i < 16; ++i) { tot += red[i]; ft += redf[i]; }
    atomicAdd(&accd[(size_t)b*ACC_STRIDE + 82], (double)tot);
    atomicAdd(&accd[(size_t)b*ACC_STRIDE + 81], (double)ft);
  }
}

__global__ void k_final(const double* __restrict__ accd, float* __restrict__ out)
{
  int t = threadIdx.x;
  double lb = 0.0;
  if (t < NIMG) {
    const double* ab = accd + (size_t)t*ACC_STRIDE;
    lb = (ab[82] + 10.0*ab[83]) / ab[84] + (ab[80] + ab[81]) * (1.0/(double)HWPX);
  }
  #pragma unroll
  for (int o = 4; o > 0; o >>= 1) lb += __shfl_down(lb, o);
  if (t == 0) out[0] = (float)(lb * 0.125);
}

extern "C" void kernel_launch(void* const* d_in, const int* in_sizes, int n_in,
                              void* d_out, int out_size, void* d_ws, size_t ws_size,
                              hipStream_t stream)
{
  const float* pred = (const float*)d_in[0];
  const int*   inst = (const int*)d_in[1];
  const int*   lab  = (const int*)d_in[2];
  float* out = (float*)d_out;

  size_t recB   = (size_t)NIMG * HWPX * sizeof(u64);         // 16.78 MB
  size_t partB  = (size_t)NIMG * NGRP * NSPLIT * 8 * NB * 4; //  8.39 MB
  size_t pstatB = (size_t)PREP_BLOCKS * 96 * sizeof(float);  //  0.10 MB
  size_t accB   = (size_t)NIMG * ACC_STRIDE * sizeof(double);
  size_t pairB  = 128 * 4 * sizeof(float);
  bool full = ws_size >= recB + partB + pstatB + accB + pairB;

  char* ws = (char*)d_ws;
  if (full) {
    u64*      rec   = (u64*)ws;
    unsigned* part  = (unsigned*)(ws + recB);
    float*    pstat = (float*)(ws + recB + partB);
    double*   accd  = (double*)(ws + recB + partB + pstatB);
    float*    pairinfo = (float*)(ws + recB + partB + pstatB + accB);
    k_prep<true><<<PREP_BLOCKS,1024,0,stream>>>(pred, inst, lab, rec, pstat);
    k_fin<<<NIMG,128,0,stream>>>(pstat, accd, pairinfo);
    k_hist<<<NIMG*NGRP*NSPLIT,1024,0,stream>>>(rec, pairinfo, part, accd);
    k_scan<<<128,1024,0,stream>>>(part, pairinfo, accd);
    k_final<<<1,64,0,stream>>>(accd, out);
  } else {
    float*    pstat = (float*)ws;
    double*   accd  = (double*)(ws + pstatB);
    float*    pairinfo = (float*)(ws + pstatB + accB);
    k_prep<false><<<PREP_BLOCKS,1024,0,stream>>>(pred, inst, lab, nullptr, pstat);
    k_fin<<<NIMG,128,0,stream>>>(pstat, accd, pairinfo);
    size_t lds18 = ((size_t)2*4097 + 2048)*4 + 128;
    k_lov_old<<<128,1024,lds18,stream>>>(pred, inst, lab, pairinfo, accd);
    k_final<<<1,64,0,stream>>>(accd, out);
  }
}